// Round 3
// baseline (174.510 us; speedup 1.0000x reference)
//
#include <hip/hip_runtime.h>
#include <math.h>

#define NROW 4096
#define NDIM 128
#define KNN 10
#define LDSS 136  // bf16 LDS row stride (128 + 8 pad -> 2-way banks, 16B aligned)

typedef __bf16 bf16x8 __attribute__((ext_vector_type(8)));
typedef float f32x4 __attribute__((ext_vector_type(4)));

__device__ inline unsigned short f2bf(float f) {  // RTNE f32->bf16
    unsigned int u = __float_as_uint(f);
    u += 0x7FFFu + ((u >> 16) & 1u);
    return (unsigned short)(u >> 16);
}

// ---------------- Kernel 1: gate, masked = x*gate, r = rowsum(masked^2) ------
__global__ __launch_bounds__(128) void k_mask(const float* __restrict__ x,
                                              const float* __restrict__ alpha,
                                              const float* __restrict__ noise,
                                              float* __restrict__ masked,
                                              float* __restrict__ r) {
    int row = blockIdx.x;
    int c = threadIdx.x;
    float g = alpha[c] + 0.5f * noise[c] + 0.5f;
    g = fminf(fmaxf(g, 0.0f), 1.0f);
    float m = x[row * NDIM + c] * g;
    masked[row * NDIM + c] = m;
    float v = m * m;
#pragma unroll
    for (int o = 32; o > 0; o >>= 1) v += __shfl_down(v, o, 64);
    __shared__ float partial[2];
    if ((c & 63) == 0) partial[c >> 6] = v;
    __syncthreads();
    if (c == 0) r[row] = partial[0] + partial[1];
}

// ---------------- Kernel 2: Dx = r_i + r_j - 2*M M^T via bf16 MFMA -----------
__global__ __launch_bounds__(256) void k_dx(const float* __restrict__ M,
                                            const float* __restrict__ r,
                                            float* __restrict__ Dx) {
    __shared__ __align__(16) __bf16 Asm[128 * LDSS];
    __shared__ __align__(16) __bf16 Bsm[128 * LDSS];
    int tid = threadIdx.x;
    int bx = blockIdx.x, by = blockIdx.y;

    {
        const float* Ap = M + (size_t)by * 128 * NDIM;
        const float* Bp = M + (size_t)bx * 128 * NDIM;
        int c = (tid & 15) * 8;
        int r0 = tid >> 4;
#pragma unroll
        for (int i = 0; i < 8; ++i) {
            int row = r0 + i * 16;
            float4 a0 = *(const float4*)(Ap + row * NDIM + c);
            float4 a1 = *(const float4*)(Ap + row * NDIM + c + 4);
            uint4 pa;
            pa.x = (unsigned)f2bf(a0.x) | ((unsigned)f2bf(a0.y) << 16);
            pa.y = (unsigned)f2bf(a0.z) | ((unsigned)f2bf(a0.w) << 16);
            pa.z = (unsigned)f2bf(a1.x) | ((unsigned)f2bf(a1.y) << 16);
            pa.w = (unsigned)f2bf(a1.z) | ((unsigned)f2bf(a1.w) << 16);
            *(uint4*)&Asm[row * LDSS + c] = pa;
            float4 b0 = *(const float4*)(Bp + row * NDIM + c);
            float4 b1 = *(const float4*)(Bp + row * NDIM + c + 4);
            uint4 pb;
            pb.x = (unsigned)f2bf(b0.x) | ((unsigned)f2bf(b0.y) << 16);
            pb.y = (unsigned)f2bf(b0.z) | ((unsigned)f2bf(b0.w) << 16);
            pb.z = (unsigned)f2bf(b1.x) | ((unsigned)f2bf(b1.y) << 16);
            pb.w = (unsigned)f2bf(b1.z) | ((unsigned)f2bf(b1.w) << 16);
            *(uint4*)&Bsm[row * LDSS + c] = pb;
        }
    }
    __syncthreads();

    int wave = tid >> 6, lane = tid & 63;
    int wr = wave >> 1, wc = wave & 1;
    int quad = lane >> 4, l15 = lane & 15;

    f32x4 acc[4][4];
#pragma unroll
    for (int i = 0; i < 4; ++i)
#pragma unroll
        for (int j = 0; j < 4; ++j) acc[i][j] = (f32x4)(0.0f);

#pragma unroll
    for (int kk = 0; kk < 128; kk += 32) {
        int ka = kk + quad * 8;
        bf16x8 af[4], bfr[4];
#pragma unroll
        for (int ti = 0; ti < 4; ++ti)
            af[ti] = *(const bf16x8*)&Asm[(wr * 64 + ti * 16 + l15) * LDSS + ka];
#pragma unroll
        for (int tj = 0; tj < 4; ++tj)
            bfr[tj] = *(const bf16x8*)&Bsm[(wc * 64 + tj * 16 + l15) * LDSS + ka];
#pragma unroll
        for (int ti = 0; ti < 4; ++ti)
#pragma unroll
            for (int tj = 0; tj < 4; ++tj)
                acc[ti][tj] = __builtin_amdgcn_mfma_f32_16x16x32_bf16(
                    af[ti], bfr[tj], acc[ti][tj], 0, 0, 0);
    }

    int gi_base = by * 128 + wr * 64;
    int gj_base = bx * 128 + wc * 64;
    float rrow[4][4], rcol[4];
#pragma unroll
    for (int ti = 0; ti < 4; ++ti)
#pragma unroll
        for (int rg = 0; rg < 4; ++rg)
            rrow[ti][rg] = r[gi_base + ti * 16 + quad * 4 + rg];
#pragma unroll
    for (int tj = 0; tj < 4; ++tj) rcol[tj] = r[gj_base + tj * 16 + l15];
#pragma unroll
    for (int ti = 0; ti < 4; ++ti)
#pragma unroll
        for (int rg = 0; rg < 4; ++rg) {
            int grow = gi_base + ti * 16 + quad * 4 + rg;
#pragma unroll
            for (int tj = 0; tj < 4; ++tj) {
                int gcol = gj_base + tj * 16 + l15;
                Dx[(size_t)grow * NROW + gcol] =
                    rrow[ti][rg] + rcol[tj] - 2.0f * acc[ti][tj][rg];
            }
        }
}

// ---------------- Kernel 3: wave-per-row 10x extract-min, no barriers --------
__global__ __launch_bounds__(256) void k_knn(const float* __restrict__ Dx,
                                             float* __restrict__ knn) {
    __shared__ float rows[4][NROW];  // 64 KB, one row per wave
    int tid = threadIdx.x;
    int wave = tid >> 6, lane = tid & 63;
    int row = blockIdx.x * 4 + wave;
    const float* drow = Dx + (size_t)row * NROW;
    float* lrow = rows[wave];

    // stream row into LDS; build lane-local argmin over its 16 float4s
    float bv = INFINITY;
    int bi = 0;
#pragma unroll
    for (int c = 0; c < 16; ++c) {
        int f4 = c * 64 + lane;
        float4 v = *(const float4*)(drow + f4 * 4);
        *(float4*)&lrow[f4 * 4] = v;
        int base = f4 * 4;
        if (v.x < bv) { bv = v.x; bi = base; }
        if (v.y < bv) { bv = v.y; bi = base + 1; }
        if (v.z < bv) { bv = v.z; bi = base + 2; }
        if (v.w < bv) { bv = v.w; bi = base + 3; }
    }
    __syncthreads();  // one barrier: publish LDS writes across lanes

#pragma unroll 1
    for (int it = 0; it < KNN; ++it) {
        // butterfly argmin (all lanes end with global min, tie-break on idx)
        float v = bv;
        int ix = bi;
#pragma unroll
        for (int o = 1; o < 64; o <<= 1) {
            float ov = __shfl_xor(v, o, 64);
            int oi = __shfl_xor(ix, o, 64);
            if (ov < v || (ov == v && oi < ix)) { v = ov; ix = oi; }
        }
        if (it == KNN - 1) {
            if (lane == 0) knn[row] = v;
        } else if (((ix >> 2) & 63) == lane) {
            // I own the extracted element: invalidate + rescan my 64 values
            lrow[ix] = INFINITY;
            bv = INFINITY;
            bi = 0;
#pragma unroll
            for (int c = 0; c < 16; ++c) {
                int f4 = c * 64 + lane;
                float4 w = *(const float4*)&lrow[f4 * 4];
                int base = f4 * 4;
                if (w.x < bv) { bv = w.x; bi = base; }
                if (w.y < bv) { bv = w.y; bi = base + 1; }
                if (w.z < bv) { bv = w.z; bi = base + 2; }
                if (w.w < bv) { bv = w.w; bi = base + 3; }
            }
        }
    }
}

// ---------------- Kernel 4: median via 3-round radix select ------------------
__device__ inline unsigned fmap(float f) {
    unsigned b = __float_as_uint(f);
    return b ^ ((b >> 31) ? 0xFFFFFFFFu : 0x80000000u);
}
__device__ inline float funmap(unsigned u) {
    unsigned b = (u & 0x80000000u) ? (u ^ 0x80000000u) : ~u;
    return __uint_as_float(b);
}

__global__ __launch_bounds__(1024) void k_sigma(const float* __restrict__ knn,
                                                float* __restrict__ scale_out) {
    __shared__ unsigned keys[NROW];
    __shared__ unsigned hist[2048];
    __shared__ unsigned s_prefix, s_R;
    __shared__ float red_f[16];
    __shared__ unsigned red_u[16];
    int tid = threadIdx.x;
    if (tid == 0) { s_prefix = 0; s_R = 2047; }
#pragma unroll
    for (int l = 0; l < 4; ++l) keys[tid + l * 1024] = fmap(knn[tid + l * 1024]);
    __syncthreads();

    const int shifts[3] = {21, 10, 0};
    const int widths[3] = {11, 11, 10};
    for (int rd = 0; rd < 3; ++rd) {
        int sh = shifts[rd], w = widths[rd];
        unsigned nb = 1u << w;
        hist[tid] = 0;
        hist[tid + 1024] = 0;
        __syncthreads();
        unsigned prefix = s_prefix;
        unsigned R = s_R;
        int hsh = sh + w;
#pragma unroll
        for (int l = 0; l < 4; ++l) {
            unsigned k = keys[tid + l * 1024];
            bool match = (rd == 0) || ((k >> hsh) == prefix);
            if (match) atomicAdd(&hist[(k >> sh) & (nb - 1u)], 1u);
        }
        __syncthreads();
        if (tid < 64) {
            unsigned chunk = nb >> 6;
            unsigned base = tid * chunk;
            unsigned lsum = 0;
            for (unsigned i = 0; i < chunk; ++i) lsum += hist[base + i];
            unsigned pfx = lsum;
#pragma unroll
            for (int o = 1; o < 64; o <<= 1) {
                unsigned v = __shfl_up(pfx, o, 64);
                if (tid >= o) pfx += v;
            }
            unsigned excl = pfx - lsum;
            if (R >= excl && R < excl + lsum) {
                unsigned cum = excl;
                for (unsigned i = 0; i < chunk; ++i) {
                    unsigned h = hist[base + i];
                    if (R < cum + h) {
                        s_prefix = (prefix << w) | (base + i);
                        s_R = R - cum;
                        break;
                    }
                    cum += h;
                }
            }
        }
        __syncthreads();
    }

    unsigned mlk = s_prefix;
    unsigned cnt = 0, mng = 0xFFFFFFFFu;
#pragma unroll
    for (int l = 0; l < 4; ++l) {
        unsigned k = keys[tid + l * 1024];
        if (k <= mlk) cnt++;
        else mng = min(mng, k);
    }
#pragma unroll
    for (int o = 32; o > 0; o >>= 1) {
        cnt += __shfl_down(cnt, o, 64);
        mng = min(mng, (unsigned)__shfl_down(mng, o, 64));
    }
    int lane = tid & 63, wid = tid >> 6;
    if (lane == 0) { red_u[wid] = cnt; red_f[wid] = __uint_as_float(mng); }
    __syncthreads();
    if (tid == 0) {
        unsigned ctot = 0, m = 0xFFFFFFFFu;
        for (int w = 0; w < 16; ++w) {
            ctot += red_u[w];
            m = min(m, __float_as_uint(red_f[w]));
        }
        float ml = funmap(mlk);
        float mu = (ctot >= 2049u) ? ml : funmap(m);
        float sigma = 0.5f * (mu + ml);
        if (sigma < 1e-8f) sigma = 1.0f;
        scale_out[0] = -1.0f / (2.0f * sigma);
    }
}

// ---------------- Kernel 5: P = exp(Dx*scale) / rowsum, in place -------------
__global__ __launch_bounds__(256) void k_norm(float* __restrict__ Dx,
                                              const float* __restrict__ scale_p) {
    int row = blockIdx.x, tid = threadIdx.x;
    float scale = scale_p[0];
    float* drow = Dx + (size_t)row * NROW;
    float4 v[4];
    float sum = 0.0f;
#pragma unroll
    for (int l = 0; l < 4; ++l) {
        v[l] = *(float4*)(drow + l * 1024 + tid * 4);
        v[l].x = __expf(v[l].x * scale);
        v[l].y = __expf(v[l].y * scale);
        v[l].z = __expf(v[l].z * scale);
        v[l].w = __expf(v[l].w * scale);
        sum += v[l].x + v[l].y + v[l].z + v[l].w;
    }
#pragma unroll
    for (int o = 32; o > 0; o >>= 1) sum += __shfl_down(sum, o, 64);
    __shared__ float ps[4];
    int lane = tid & 63, wid = tid >> 6;
    if (lane == 0) ps[wid] = sum;
    __syncthreads();
    float inv = 1.0f / (ps[0] + ps[1] + ps[2] + ps[3]);
#pragma unroll
    for (int l = 0; l < 4; ++l) {
        v[l].x *= inv;
        v[l].y *= inv;
        v[l].z *= inv;
        v[l].w *= inv;
        *(float4*)(drow + l * 1024 + tid * 4) = v[l];
    }
}

extern "C" void kernel_launch(void* const* d_in, const int* in_sizes, int n_in,
                              void* d_out, int out_size, void* d_ws, size_t ws_size,
                              hipStream_t stream) {
    const float* x = (const float*)d_in[0];
    const float* alpha = (const float*)d_in[1];
    const float* noise = (const float*)d_in[2];
    float* out = (float*)d_out;
    float* P = out;
    float* masked = out + (size_t)NROW * NROW;
    float* ws = (float*)d_ws;
    float* r = ws;
    float* knn = ws + NROW;
    float* scale = ws + 2 * NROW;

    k_mask<<<NROW, 128, 0, stream>>>(x, alpha, noise, masked, r);
    k_dx<<<dim3(NROW / 128, NROW / 128), 256, 0, stream>>>(masked, r, P);
    k_knn<<<NROW / 4, 256, 0, stream>>>(P, knn);
    k_sigma<<<1, 1024, 0, stream>>>(knn, scale);
    k_norm<<<NROW, 256, 0, stream>>>(P, scale);
}

// Round 4
// 150.435 us; speedup vs baseline: 1.1600x; 1.1600x over previous
//
#include <hip/hip_runtime.h>
#include <math.h>

#define NROW 4096
#define NDIM 128
#define KNN 10
#define LDSS 136  // bf16 LDS row stride (128 + 8 pad -> 2-way banks, 16B aligned)

typedef __bf16 bf16x8 __attribute__((ext_vector_type(8)));
typedef float f32x4 __attribute__((ext_vector_type(4)));

__device__ inline unsigned short f2bf(float f) {  // RTNE f32->bf16
    unsigned int u = __float_as_uint(f);
    u += 0x7FFFu + ((u >> 16) & 1u);
    return (unsigned short)(u >> 16);
}

// ---------------- Kernel 1: gate, masked = x*gate, r = rowsum(masked^2) ------
__global__ __launch_bounds__(128) void k_mask(const float* __restrict__ x,
                                              const float* __restrict__ alpha,
                                              const float* __restrict__ noise,
                                              float* __restrict__ masked,
                                              float* __restrict__ r) {
    int row = blockIdx.x;
    int c = threadIdx.x;
    float g = alpha[c] + 0.5f * noise[c] + 0.5f;
    g = fminf(fmaxf(g, 0.0f), 1.0f);
    float m = x[row * NDIM + c] * g;
    masked[row * NDIM + c] = m;
    float v = m * m;
#pragma unroll
    for (int o = 32; o > 0; o >>= 1) v += __shfl_down(v, o, 64);
    __shared__ float partial[2];
    if ((c & 63) == 0) partial[c >> 6] = v;
    __syncthreads();
    if (c == 0) r[row] = partial[0] + partial[1];
}

// ---------------- Kernel 2: Dx = r_i + r_j - 2*M M^T via bf16 MFMA -----------
__global__ __launch_bounds__(256) void k_dx(const float* __restrict__ M,
                                            const float* __restrict__ r,
                                            float* __restrict__ Dx) {
    __shared__ __align__(16) __bf16 Asm[128 * LDSS];
    __shared__ __align__(16) __bf16 Bsm[128 * LDSS];
    int tid = threadIdx.x;
    int bx = blockIdx.x, by = blockIdx.y;

    {
        const float* Ap = M + (size_t)by * 128 * NDIM;
        const float* Bp = M + (size_t)bx * 128 * NDIM;
        int c = (tid & 15) * 8;
        int r0 = tid >> 4;
#pragma unroll
        for (int i = 0; i < 8; ++i) {
            int row = r0 + i * 16;
            float4 a0 = *(const float4*)(Ap + row * NDIM + c);
            float4 a1 = *(const float4*)(Ap + row * NDIM + c + 4);
            uint4 pa;
            pa.x = (unsigned)f2bf(a0.x) | ((unsigned)f2bf(a0.y) << 16);
            pa.y = (unsigned)f2bf(a0.z) | ((unsigned)f2bf(a0.w) << 16);
            pa.z = (unsigned)f2bf(a1.x) | ((unsigned)f2bf(a1.y) << 16);
            pa.w = (unsigned)f2bf(a1.z) | ((unsigned)f2bf(a1.w) << 16);
            *(uint4*)&Asm[row * LDSS + c] = pa;
            float4 b0 = *(const float4*)(Bp + row * NDIM + c);
            float4 b1 = *(const float4*)(Bp + row * NDIM + c + 4);
            uint4 pb;
            pb.x = (unsigned)f2bf(b0.x) | ((unsigned)f2bf(b0.y) << 16);
            pb.y = (unsigned)f2bf(b0.z) | ((unsigned)f2bf(b0.w) << 16);
            pb.z = (unsigned)f2bf(b1.x) | ((unsigned)f2bf(b1.y) << 16);
            pb.w = (unsigned)f2bf(b1.z) | ((unsigned)f2bf(b1.w) << 16);
            *(uint4*)&Bsm[row * LDSS + c] = pb;
        }
    }
    __syncthreads();

    int wave = tid >> 6, lane = tid & 63;
    int wr = wave >> 1, wc = wave & 1;
    int quad = lane >> 4, l15 = lane & 15;

    f32x4 acc[4][4];
#pragma unroll
    for (int i = 0; i < 4; ++i)
#pragma unroll
        for (int j = 0; j < 4; ++j) acc[i][j] = (f32x4)(0.0f);

#pragma unroll
    for (int kk = 0; kk < 128; kk += 32) {
        int ka = kk + quad * 8;
        bf16x8 af[4], bfr[4];
#pragma unroll
        for (int ti = 0; ti < 4; ++ti)
            af[ti] = *(const bf16x8*)&Asm[(wr * 64 + ti * 16 + l15) * LDSS + ka];
#pragma unroll
        for (int tj = 0; tj < 4; ++tj)
            bfr[tj] = *(const bf16x8*)&Bsm[(wc * 64 + tj * 16 + l15) * LDSS + ka];
#pragma unroll
        for (int ti = 0; ti < 4; ++ti)
#pragma unroll
            for (int tj = 0; tj < 4; ++tj)
                acc[ti][tj] = __builtin_amdgcn_mfma_f32_16x16x32_bf16(
                    af[ti], bfr[tj], acc[ti][tj], 0, 0, 0);
    }

    int gi_base = by * 128 + wr * 64;
    int gj_base = bx * 128 + wc * 64;
    float rrow[4][4], rcol[4];
#pragma unroll
    for (int ti = 0; ti < 4; ++ti)
#pragma unroll
        for (int rg = 0; rg < 4; ++rg)
            rrow[ti][rg] = r[gi_base + ti * 16 + quad * 4 + rg];
#pragma unroll
    for (int tj = 0; tj < 4; ++tj) rcol[tj] = r[gj_base + tj * 16 + l15];
#pragma unroll
    for (int ti = 0; ti < 4; ++ti)
#pragma unroll
        for (int rg = 0; rg < 4; ++rg) {
            int grow = gi_base + ti * 16 + quad * 4 + rg;
#pragma unroll
            for (int tj = 0; tj < 4; ++tj) {
                int gcol = gj_base + tj * 16 + l15;
                Dx[(size_t)grow * NROW + gcol] =
                    rrow[ti][rg] + rcol[tj] - 2.0f * acc[ti][tj][rg];
            }
        }
}

// ------- Kernel 3: wave-per-row, register top-10 + shuffle merge, no LDS -----
__global__ __launch_bounds__(256) void k_knn(const float* __restrict__ Dx,
                                             float* __restrict__ knn) {
    int tid = threadIdx.x;
    int wave = tid >> 6, lane = tid & 63;
    int row = blockIdx.x * 4 + wave;
    const float* drow = Dx + (size_t)row * NROW;

    // per-lane 10 smallest of my 64 values, sorted ascending (branch-free)
    float t[KNN];
#pragma unroll
    for (int j = 0; j < KNN; ++j) t[j] = INFINITY;

#pragma unroll
    for (int c = 0; c < 16; ++c) {
        float4 v4 = *(const float4*)(drow + (c * 64 + lane) * 4);
        float vv[4] = {v4.x, v4.y, v4.z, v4.w};
#pragma unroll
        for (int e = 0; e < 4; ++e) {
            float cv = vv[e];
#pragma unroll
            for (int j = 0; j < KNN; ++j) {
                float lo = fminf(t[j], cv);
                cv = fmaxf(t[j], cv);
                t[j] = lo;
            }
        }
    }

    // 10 rounds: butterfly argmin over lane heads; winner pops its list
#pragma unroll
    for (int r = 0; r < KNN; ++r) {
        float v = t[0];
        int src = lane;
#pragma unroll
        for (int o = 1; o < 64; o <<= 1) {
            float ov = __shfl_xor(v, o, 64);
            int osrc = __shfl_xor(src, o, 64);
            if (ov < v || (ov == v && osrc < src)) { v = ov; src = osrc; }
        }
        if (r == KNN - 1) {
            if (lane == 0) knn[row] = v;
        } else if (src == lane) {
#pragma unroll
            for (int j = 0; j < KNN - 1; ++j) t[j] = t[j + 1];
            t[KNN - 1] = INFINITY;
        }
    }
}

// ---------------- Kernel 4: median via 3-round radix select ------------------
__device__ inline unsigned fmap(float f) {
    unsigned b = __float_as_uint(f);
    return b ^ ((b >> 31) ? 0xFFFFFFFFu : 0x80000000u);
}
__device__ inline float funmap(unsigned u) {
    unsigned b = (u & 0x80000000u) ? (u ^ 0x80000000u) : ~u;
    return __uint_as_float(b);
}

__global__ __launch_bounds__(1024) void k_sigma(const float* __restrict__ knn,
                                                float* __restrict__ scale_out) {
    __shared__ unsigned keys[NROW];
    __shared__ unsigned hist[2048];
    __shared__ unsigned s_prefix, s_R;
    __shared__ float red_f[16];
    __shared__ unsigned red_u[16];
    int tid = threadIdx.x;
    if (tid == 0) { s_prefix = 0; s_R = 2047; }
#pragma unroll
    for (int l = 0; l < 4; ++l) keys[tid + l * 1024] = fmap(knn[tid + l * 1024]);
    __syncthreads();

    const int shifts[3] = {21, 10, 0};
    const int widths[3] = {11, 11, 10};
    for (int rd = 0; rd < 3; ++rd) {
        int sh = shifts[rd], w = widths[rd];
        unsigned nb = 1u << w;
        hist[tid] = 0;
        hist[tid + 1024] = 0;
        __syncthreads();
        unsigned prefix = s_prefix;
        unsigned R = s_R;
        int hsh = sh + w;
#pragma unroll
        for (int l = 0; l < 4; ++l) {
            unsigned k = keys[tid + l * 1024];
            bool match = (rd == 0) || ((k >> hsh) == prefix);
            if (match) atomicAdd(&hist[(k >> sh) & (nb - 1u)], 1u);
        }
        __syncthreads();
        if (tid < 64) {
            unsigned chunk = nb >> 6;
            unsigned base = tid * chunk;
            unsigned lsum = 0;
            for (unsigned i = 0; i < chunk; ++i) lsum += hist[base + i];
            unsigned pfx = lsum;
#pragma unroll
            for (int o = 1; o < 64; o <<= 1) {
                unsigned v = __shfl_up(pfx, o, 64);
                if (tid >= o) pfx += v;
            }
            unsigned excl = pfx - lsum;
            if (R >= excl && R < excl + lsum) {
                unsigned cum = excl;
                for (unsigned i = 0; i < chunk; ++i) {
                    unsigned h = hist[base + i];
                    if (R < cum + h) {
                        s_prefix = (prefix << w) | (base + i);
                        s_R = R - cum;
                        break;
                    }
                    cum += h;
                }
            }
        }
        __syncthreads();
    }

    unsigned mlk = s_prefix;
    unsigned cnt = 0, mng = 0xFFFFFFFFu;
#pragma unroll
    for (int l = 0; l < 4; ++l) {
        unsigned k = keys[tid + l * 1024];
        if (k <= mlk) cnt++;
        else mng = min(mng, k);
    }
#pragma unroll
    for (int o = 32; o > 0; o >>= 1) {
        cnt += __shfl_down(cnt, o, 64);
        mng = min(mng, (unsigned)__shfl_down(mng, o, 64));
    }
    int lane = tid & 63, wid = tid >> 6;
    if (lane == 0) { red_u[wid] = cnt; red_f[wid] = __uint_as_float(mng); }
    __syncthreads();
    if (tid == 0) {
        unsigned ctot = 0, m = 0xFFFFFFFFu;
        for (int w = 0; w < 16; ++w) {
            ctot += red_u[w];
            m = min(m, __float_as_uint(red_f[w]));
        }
        float ml = funmap(mlk);
        float mu = (ctot >= 2049u) ? ml : funmap(m);
        float sigma = 0.5f * (mu + ml);
        if (sigma < 1e-8f) sigma = 1.0f;
        scale_out[0] = -1.0f / (2.0f * sigma);
    }
}

// ---------------- Kernel 5: P = exp(Dx*scale) / rowsum, in place -------------
__global__ __launch_bounds__(256) void k_norm(float* __restrict__ Dx,
                                              const float* __restrict__ scale_p) {
    int row = blockIdx.x, tid = threadIdx.x;
    float scale = scale_p[0];
    float* drow = Dx + (size_t)row * NROW;
    float4 v[4];
    float sum = 0.0f;
#pragma unroll
    for (int l = 0; l < 4; ++l) {
        v[l] = *(float4*)(drow + l * 1024 + tid * 4);
        v[l].x = __expf(v[l].x * scale);
        v[l].y = __expf(v[l].y * scale);
        v[l].z = __expf(v[l].z * scale);
        v[l].w = __expf(v[l].w * scale);
        sum += v[l].x + v[l].y + v[l].z + v[l].w;
    }
#pragma unroll
    for (int o = 32; o > 0; o >>= 1) sum += __shfl_down(sum, o, 64);
    __shared__ float ps[4];
    int lane = tid & 63, wid = tid >> 6;
    if (lane == 0) ps[wid] = sum;
    __syncthreads();
    float inv = 1.0f / (ps[0] + ps[1] + ps[2] + ps[3]);
#pragma unroll
    for (int l = 0; l < 4; ++l) {
        v[l].x *= inv;
        v[l].y *= inv;
        v[l].z *= inv;
        v[l].w *= inv;
        *(float4*)(drow + l * 1024 + tid * 4) = v[l];
    }
}

extern "C" void kernel_launch(void* const* d_in, const int* in_sizes, int n_in,
                              void* d_out, int out_size, void* d_ws, size_t ws_size,
                              hipStream_t stream) {
    const float* x = (const float*)d_in[0];
    const float* alpha = (const float*)d_in[1];
    const float* noise = (const float*)d_in[2];
    float* out = (float*)d_out;
    float* P = out;
    float* masked = out + (size_t)NROW * NROW;
    float* ws = (float*)d_ws;
    float* r = ws;
    float* knn = ws + NROW;
    float* scale = ws + 2 * NROW;

    k_mask<<<NROW, 128, 0, stream>>>(x, alpha, noise, masked, r);
    k_dx<<<dim3(NROW / 128, NROW / 128), 256, 0, stream>>>(masked, r, P);
    k_knn<<<NROW / 4, 256, 0, stream>>>(P, knn);
    k_sigma<<<1, 1024, 0, stream>>>(knn, scale);
    k_norm<<<NROW, 256, 0, stream>>>(P, scale);
}

// Round 5
// 145.917 us; speedup vs baseline: 1.1959x; 1.0310x over previous
//
#include <hip/hip_runtime.h>
#include <math.h>

#define NROW 4096
#define NDIM 128
#define KNN 10
#define LDSS 136  // bf16 LDS row stride (128 + 8 pad -> 2-way banks, 16B aligned)

typedef __bf16 bf16x8 __attribute__((ext_vector_type(8)));
typedef unsigned short u16x8 __attribute__((ext_vector_type(8)));
typedef float f32x4 __attribute__((ext_vector_type(4)));

__device__ inline unsigned short f2bf(float f) {  // RTNE f32->bf16
    unsigned int u = __float_as_uint(f);
    u += 0x7FFFu + ((u >> 16) & 1u);
    return (unsigned short)(u >> 16);
}
__device__ inline float bf2f(unsigned short u) {
    return __uint_as_float((unsigned)u << 16);
}

// Dx intermediate (bf16) lives in the tail half of each f32 P-row slot:
//   bf16 row i = (__bf16*)(P + i*NROW + NROW/2), 4096 bf16 = 8 KB.

// ---------------- Kernel 1: gate, masked = x*gate, r = rowsum(masked^2) ------
__global__ __launch_bounds__(128) void k_mask(const float* __restrict__ x,
                                              const float* __restrict__ alpha,
                                              const float* __restrict__ noise,
                                              float* __restrict__ masked,
                                              float* __restrict__ r) {
    int row = blockIdx.x;
    int c = threadIdx.x;
    float g = alpha[c] + 0.5f * noise[c] + 0.5f;
    g = fminf(fmaxf(g, 0.0f), 1.0f);
    float m = x[row * NDIM + c] * g;
    masked[row * NDIM + c] = m;
    float v = m * m;
#pragma unroll
    for (int o = 32; o > 0; o >>= 1) v += __shfl_down(v, o, 64);
    __shared__ float partial[2];
    if ((c & 63) == 0) partial[c >> 6] = v;
    __syncthreads();
    if (c == 0) r[row] = partial[0] + partial[1];
}

// ------- Kernel 2: Dx = r_i + r_j - 2*M M^T via bf16 MFMA, bf16 output ------
__global__ __launch_bounds__(256) void k_dx(const float* __restrict__ M,
                                            const float* __restrict__ r,
                                            float* __restrict__ P) {
    __shared__ __align__(16) __bf16 Asm[128 * LDSS];
    __shared__ __align__(16) __bf16 Bsm[128 * LDSS];
    int tid = threadIdx.x;
    int bx = blockIdx.x, by = blockIdx.y;

    {
        const float* Ap = M + (size_t)by * 128 * NDIM;
        const float* Bp = M + (size_t)bx * 128 * NDIM;
        int c = (tid & 15) * 8;
        int r0 = tid >> 4;
#pragma unroll
        for (int i = 0; i < 8; ++i) {
            int row = r0 + i * 16;
            float4 a0 = *(const float4*)(Ap + row * NDIM + c);
            float4 a1 = *(const float4*)(Ap + row * NDIM + c + 4);
            uint4 pa;
            pa.x = (unsigned)f2bf(a0.x) | ((unsigned)f2bf(a0.y) << 16);
            pa.y = (unsigned)f2bf(a0.z) | ((unsigned)f2bf(a0.w) << 16);
            pa.z = (unsigned)f2bf(a1.x) | ((unsigned)f2bf(a1.y) << 16);
            pa.w = (unsigned)f2bf(a1.z) | ((unsigned)f2bf(a1.w) << 16);
            *(uint4*)&Asm[row * LDSS + c] = pa;
            float4 b0 = *(const float4*)(Bp + row * NDIM + c);
            float4 b1 = *(const float4*)(Bp + row * NDIM + c + 4);
            uint4 pb;
            pb.x = (unsigned)f2bf(b0.x) | ((unsigned)f2bf(b0.y) << 16);
            pb.y = (unsigned)f2bf(b0.z) | ((unsigned)f2bf(b0.w) << 16);
            pb.z = (unsigned)f2bf(b1.x) | ((unsigned)f2bf(b1.y) << 16);
            pb.w = (unsigned)f2bf(b1.z) | ((unsigned)f2bf(b1.w) << 16);
            *(uint4*)&Bsm[row * LDSS + c] = pb;
        }
    }
    __syncthreads();

    int wave = tid >> 6, lane = tid & 63;
    int wr = wave >> 1, wc = wave & 1;
    int quad = lane >> 4, l15 = lane & 15;

    f32x4 acc[4][4];
#pragma unroll
    for (int i = 0; i < 4; ++i)
#pragma unroll
        for (int j = 0; j < 4; ++j) acc[i][j] = (f32x4)(0.0f);

#pragma unroll
    for (int kk = 0; kk < 128; kk += 32) {
        int ka = kk + quad * 8;
        bf16x8 af[4], bfr[4];
#pragma unroll
        for (int ti = 0; ti < 4; ++ti)
            af[ti] = *(const bf16x8*)&Asm[(wr * 64 + ti * 16 + l15) * LDSS + ka];
#pragma unroll
        for (int tj = 0; tj < 4; ++tj)
            bfr[tj] = *(const bf16x8*)&Bsm[(wc * 64 + tj * 16 + l15) * LDSS + ka];
#pragma unroll
        for (int ti = 0; ti < 4; ++ti)
#pragma unroll
            for (int tj = 0; tj < 4; ++tj)
                acc[ti][tj] = __builtin_amdgcn_mfma_f32_16x16x32_bf16(
                    af[ti], bfr[tj], acc[ti][tj], 0, 0, 0);
    }

    int gi_base = by * 128 + wr * 64;
    int gj_base = bx * 128 + wc * 64;
    float rrow[4][4], rcol[4];
#pragma unroll
    for (int ti = 0; ti < 4; ++ti)
#pragma unroll
        for (int rg = 0; rg < 4; ++rg)
            rrow[ti][rg] = r[gi_base + ti * 16 + quad * 4 + rg];
#pragma unroll
    for (int tj = 0; tj < 4; ++tj) rcol[tj] = r[gj_base + tj * 16 + l15];
#pragma unroll
    for (int ti = 0; ti < 4; ++ti)
#pragma unroll
        for (int rg = 0; rg < 4; ++rg) {
            int grow = gi_base + ti * 16 + quad * 4 + rg;
            __bf16* brow = (__bf16*)(P + (size_t)grow * NROW + NROW / 2);
#pragma unroll
            for (int tj = 0; tj < 4; ++tj) {
                int gcol = gj_base + tj * 16 + l15;
                float d = rrow[ti][rg] + rcol[tj] - 2.0f * acc[ti][tj][rg];
                ((unsigned short*)brow)[gcol] = f2bf(d);
            }
        }
}

// ------- Kernel 3: wave-per-row, register top-10 + shuffle merge (bf16 in) ---
__global__ __launch_bounds__(256) void k_knn(const float* __restrict__ P,
                                             float* __restrict__ knn) {
    int tid = threadIdx.x;
    int wave = tid >> 6, lane = tid & 63;
    int row = blockIdx.x * 4 + wave;
    const unsigned short* drow =
        (const unsigned short*)(P + (size_t)row * NROW + NROW / 2);

    float t[KNN];
#pragma unroll
    for (int j = 0; j < KNN; ++j) t[j] = INFINITY;

#pragma unroll
    for (int c = 0; c < 8; ++c) {
        u16x8 v8 = *(const u16x8*)(drow + (c * 64 + lane) * 8);
#pragma unroll
        for (int e = 0; e < 8; ++e) {
            float cv = bf2f(v8[e]);
#pragma unroll
            for (int j = 0; j < KNN; ++j) {
                float lo = fminf(t[j], cv);
                cv = fmaxf(t[j], cv);
                t[j] = lo;
            }
        }
    }

#pragma unroll
    for (int r = 0; r < KNN; ++r) {
        float v = t[0];
        int src = lane;
#pragma unroll
        for (int o = 1; o < 64; o <<= 1) {
            float ov = __shfl_xor(v, o, 64);
            int osrc = __shfl_xor(src, o, 64);
            if (ov < v || (ov == v && osrc < src)) { v = ov; src = osrc; }
        }
        if (r == KNN - 1) {
            if (lane == 0) knn[row] = v;
        } else if (src == lane) {
#pragma unroll
            for (int j = 0; j < KNN - 1; ++j) t[j] = t[j + 1];
            t[KNN - 1] = INFINITY;
        }
    }
}

// ---------------- Kernel 4: median via 3-round radix select ------------------
__device__ inline unsigned fmap(float f) {
    unsigned b = __float_as_uint(f);
    return b ^ ((b >> 31) ? 0xFFFFFFFFu : 0x80000000u);
}
__device__ inline float funmap(unsigned u) {
    unsigned b = (u & 0x80000000u) ? (u ^ 0x80000000u) : ~u;
    return __uint_as_float(b);
}

__global__ __launch_bounds__(1024) void k_sigma(const float* __restrict__ knn,
                                                float* __restrict__ scale_out) {
    __shared__ unsigned keys[NROW];
    __shared__ unsigned hist[2048];
    __shared__ unsigned s_prefix, s_R;
    __shared__ float red_f[16];
    __shared__ unsigned red_u[16];
    int tid = threadIdx.x;
    if (tid == 0) { s_prefix = 0; s_R = 2047; }
#pragma unroll
    for (int l = 0; l < 4; ++l) keys[tid + l * 1024] = fmap(knn[tid + l * 1024]);
    __syncthreads();

    const int shifts[3] = {21, 10, 0};
    const int widths[3] = {11, 11, 10};
    for (int rd = 0; rd < 3; ++rd) {
        int sh = shifts[rd], w = widths[rd];
        unsigned nb = 1u << w;
        hist[tid] = 0;
        hist[tid + 1024] = 0;
        __syncthreads();
        unsigned prefix = s_prefix;
        unsigned R = s_R;
        int hsh = sh + w;
#pragma unroll
        for (int l = 0; l < 4; ++l) {
            unsigned k = keys[tid + l * 1024];
            bool match = (rd == 0) || ((k >> hsh) == prefix);
            if (match) atomicAdd(&hist[(k >> sh) & (nb - 1u)], 1u);
        }
        __syncthreads();
        if (tid < 64) {
            unsigned chunk = nb >> 6;
            unsigned base = tid * chunk;
            unsigned lsum = 0;
            for (unsigned i = 0; i < chunk; ++i) lsum += hist[base + i];
            unsigned pfx = lsum;
#pragma unroll
            for (int o = 1; o < 64; o <<= 1) {
                unsigned v = __shfl_up(pfx, o, 64);
                if (tid >= o) pfx += v;
            }
            unsigned excl = pfx - lsum;
            if (R >= excl && R < excl + lsum) {
                unsigned cum = excl;
                for (unsigned i = 0; i < chunk; ++i) {
                    unsigned h = hist[base + i];
                    if (R < cum + h) {
                        s_prefix = (prefix << w) | (base + i);
                        s_R = R - cum;
                        break;
                    }
                    cum += h;
                }
            }
        }
        __syncthreads();
    }

    unsigned mlk = s_prefix;
    unsigned cnt = 0, mng = 0xFFFFFFFFu;
#pragma unroll
    for (int l = 0; l < 4; ++l) {
        unsigned k = keys[tid + l * 1024];
        if (k <= mlk) cnt++;
        else mng = min(mng, k);
    }
#pragma unroll
    for (int o = 32; o > 0; o >>= 1) {
        cnt += __shfl_down(cnt, o, 64);
        mng = min(mng, (unsigned)__shfl_down(mng, o, 64));
    }
    int lane = tid & 63, wid = tid >> 6;
    if (lane == 0) { red_u[wid] = cnt; red_f[wid] = __uint_as_float(mng); }
    __syncthreads();
    if (tid == 0) {
        unsigned ctot = 0, m = 0xFFFFFFFFu;
        for (int w = 0; w < 16; ++w) {
            ctot += red_u[w];
            m = min(m, __float_as_uint(red_f[w]));
        }
        float ml = funmap(mlk);
        float mu = (ctot >= 2049u) ? ml : funmap(m);
        float sigma = 0.5f * (mu + ml);
        if (sigma < 1e-8f) sigma = 1.0f;
        scale_out[0] = -1.0f / (2.0f * sigma);
    }
}

// ------- Kernel 5: P-row = exp(bf16Dx*scale)/rowsum, reads own tail, f32 out -
__global__ __launch_bounds__(256) void k_norm(float* __restrict__ P,
                                              const float* __restrict__ scale_p) {
    int row = blockIdx.x, tid = threadIdx.x;
    float scale = scale_p[0];
    float* drow = P + (size_t)row * NROW;
    const unsigned short* brow = (const unsigned short*)(drow + NROW / 2);

    // each thread: 16 contiguous values
    u16x8 a = *(const u16x8*)(brow + tid * 16);
    u16x8 b = *(const u16x8*)(brow + tid * 16 + 8);
    float v[16];
#pragma unroll
    for (int e = 0; e < 8; ++e) v[e] = __expf(bf2f(a[e]) * scale);
#pragma unroll
    for (int e = 0; e < 8; ++e) v[8 + e] = __expf(bf2f(b[e]) * scale);
    float sum = 0.0f;
#pragma unroll
    for (int e = 0; e < 16; ++e) sum += v[e];
#pragma unroll
    for (int o = 32; o > 0; o >>= 1) sum += __shfl_down(sum, o, 64);
    __shared__ float ps[4];
    int lane = tid & 63, wid = tid >> 6;
    if (lane == 0) ps[wid] = sum;
    __syncthreads();  // also orders all bf16 reads before the f32 overwrite
    float inv = 1.0f / (ps[0] + ps[1] + ps[2] + ps[3]);
#pragma unroll
    for (int l = 0; l < 4; ++l) {
        float4 o4;
        o4.x = v[l * 4 + 0] * inv;
        o4.y = v[l * 4 + 1] * inv;
        o4.z = v[l * 4 + 2] * inv;
        o4.w = v[l * 4 + 3] * inv;
        *(float4*)(drow + tid * 16 + l * 4) = o4;
    }
}

extern "C" void kernel_launch(void* const* d_in, const int* in_sizes, int n_in,
                              void* d_out, int out_size, void* d_ws, size_t ws_size,
                              hipStream_t stream) {
    const float* x = (const float*)d_in[0];
    const float* alpha = (const float*)d_in[1];
    const float* noise = (const float*)d_in[2];
    float* out = (float*)d_out;
    float* P = out;
    float* masked = out + (size_t)NROW * NROW;
    float* ws = (float*)d_ws;
    float* r = ws;
    float* knn = ws + NROW;
    float* scale = ws + 2 * NROW;

    k_mask<<<NROW, 128, 0, stream>>>(x, alpha, noise, masked, r);
    k_dx<<<dim3(NROW / 128, NROW / 128), 256, 0, stream>>>(masked, r, P);
    k_knn<<<NROW / 4, 256, 0, stream>>>(P, knn);
    k_sigma<<<1, 1024, 0, stream>>>(knn, scale);
    k_norm<<<NROW, 256, 0, stream>>>(P, scale);
}